// Round 1
// baseline (444.038 us; speedup 1.0000x reference)
//
#include <hip/hip_runtime.h>
#include <hip/hip_bf16.h>

// Problem dims (fixed by reference): B=512, Q=64, S=36, D=1024, SIM=256
#define BB 512
#define QQ 64
#define SS 36
#define DD 1024
#define SIM 256

typedef unsigned short u16x8 __attribute__((ext_vector_type(8)));
typedef __bf16 bf16x8 __attribute__((ext_vector_type(8)));
typedef float f32x4 __attribute__((ext_vector_type(4)));

__device__ __forceinline__ unsigned short f2bf(float f) {
  unsigned u = __float_as_uint(f);
  u += 0x7FFFu + ((u >> 16) & 1u);   // round-to-nearest-even
  return (unsigned short)(u >> 16);
}
__device__ __forceinline__ float bf2f(unsigned short h) {
  return __uint_as_float(((unsigned)h) << 16);
}

// ---------------------------------------------------------------------------
// K1: per-batch scores -> leaky -> l2norm over Q -> softmax over S
// grid = 512, block = 256 (4 waves). Writes attn probs (B,Q,S) f32 to ws.
// ---------------------------------------------------------------------------
__global__ __launch_bounds__(256) void k1_attn(
    const float* __restrict__ query, const float* __restrict__ context,
    const float* __restrict__ matrix, const int* __restrict__ smoothp,
    float* __restrict__ attn) {
  __shared__ float qm_t[64][65];   // [d_local][q], transposed, +1 pad
  __shared__ float ctx_s[36][68];  // [s][d_local], float4-aligned rows
  __shared__ float sc[36][65];     // scores [s][q]

  const int t = threadIdx.x;
  const int bb = blockIdx.x;
  const int q = t & 63, sg = t >> 6;
  const float smf = (float)smoothp[0];

  float acc[9];
#pragma unroll
  for (int j = 0; j < 9; ++j) acc[j] = 0.f;

  for (int ch = 0; ch < 16; ++ch) {
    const int d0 = ch * 64;
    // stage qm = query*matrix, transposed into [d][q]
#pragma unroll
    for (int i = 0; i < 4; ++i) {
      int idx = t + 256 * i;
      int qq = idx >> 4, c4 = idx & 15;
      size_t base = ((size_t)bb * QQ + qq) * DD + d0 + c4 * 4;
      const float4 qv = *(const float4*)&query[base];
      const float4 mv = *(const float4*)&matrix[base];
      qm_t[c4 * 4 + 0][qq] = qv.x * mv.x;
      qm_t[c4 * 4 + 1][qq] = qv.y * mv.y;
      qm_t[c4 * 4 + 2][qq] = qv.z * mv.z;
      qm_t[c4 * 4 + 3][qq] = qv.w * mv.w;
    }
    // stage context chunk [s][d]
#pragma unroll
    for (int i = 0; i < 9; ++i) {
      int idx = t + 256 * i;
      int s2 = idx >> 6, c = idx & 63;
      ctx_s[s2][c] = context[((size_t)bb * SS + s2) * DD + d0 + c];
    }
    __syncthreads();
    // scores: thread -> (q, s = sg+4j)
#pragma unroll
    for (int c4 = 0; c4 < 16; ++c4) {
      float q0 = qm_t[c4 * 4 + 0][q];
      float q1 = qm_t[c4 * 4 + 1][q];
      float q2 = qm_t[c4 * 4 + 2][q];
      float q3 = qm_t[c4 * 4 + 3][q];
#pragma unroll
      for (int j = 0; j < 9; ++j) {
        const float4 cv = *(const float4*)&ctx_s[sg + 4 * j][c4 * 4];
        acc[j] = fmaf(cv.x, q0, acc[j]);
        acc[j] = fmaf(cv.y, q1, acc[j]);
        acc[j] = fmaf(cv.z, q2, acc[j]);
        acc[j] = fmaf(cv.w, q3, acc[j]);
      }
    }
    __syncthreads();
  }
  // leaky relu, store scores
#pragma unroll
  for (int j = 0; j < 9; ++j) {
    float v = acc[j];
    v = v > 0.f ? v : 0.1f * v;
    sc[sg + 4 * j][q] = v;
  }
  __syncthreads();
  // l2norm over q per row s
  if (t < 36) {
    float ssum = 0.f;
    for (int qi = 0; qi < 64; ++qi) { float v = sc[t][qi]; ssum = fmaf(v, v, ssum); }
    float rn = 1.f / (sqrtf(ssum) + 1e-8f);
    for (int qi = 0; qi < 64; ++qi) sc[t][qi] *= rn;
  }
  __syncthreads();
  // softmax over s per column q, write probs to ws (B,Q,S)
  if (t < 64) {
    float mx = -1e30f;
    for (int s2 = 0; s2 < 36; ++s2) mx = fmaxf(mx, sc[s2][t]);
    float sum = 0.f;
    for (int s2 = 0; s2 < 36; ++s2) {
      float e = __expf((sc[s2][t] - mx) * smf);
      sc[s2][t] = e;
      sum += e;
    }
    float rs = 1.f / sum;
    size_t base = ((size_t)bb * QQ + t) * SS;
    for (int s2 = 0; s2 < 36; ++s2) attn[base + s2] = sc[s2][t] * rs;
  }
}

// ---------------------------------------------------------------------------
// K2: per-batch wc -> l2norm -> A=(q-wc)^2 (bf16) -> MFMA GEMM with W -> +b,
// l2norm over SIM -> out. grid = 512, block = 1024 (16 waves), dyn LDS.
// LDS layout: A16 [64][1032] bf16 @0 (132096B) | Wl [256][40] bf16 @132096
//             bias[256] f32 @152576 | norms[64] f32 @153600. Total 153856.
// ---------------------------------------------------------------------------
#define K2_LDS 153856

__global__ __launch_bounds__(1024) void k2_fused(
    const float* __restrict__ query, const float* __restrict__ context,
    const float* __restrict__ Wm, const float* __restrict__ bvec,
    const float* __restrict__ attn, float* __restrict__ out) {
  extern __shared__ char smem[];
  unsigned short* A16 = (unsigned short*)smem;             // [64][1032]
  unsigned short* Wl = (unsigned short*)(smem + 132096);   // [256][40]
  float* bias = (float*)(smem + 152576);                   // [256]
  float* norms = (float*)(smem + 153600);                  // [64]

  const int t = threadIdx.x, bb = blockIdx.x;
  const int lane = t & 63, w = t >> 6;

  if (t < 256) bias[t] = bvec[t];

  // context distributed thread<->d: ctxreg[s] = ctx[b][s][t]
  float ctxreg[36];
#pragma unroll
  for (int s = 0; s < 36; ++s)
    ctxreg[s] = context[((size_t)bb * SS + s) * DD + t];

  // P1: wc rows (q in 4 quarters of 16), stash bf16 into A16
  for (int r = 0; r < 4; ++r) {
    float wc[16];
#pragma unroll
    for (int i = 0; i < 16; ++i) {
      const float* ap = attn + ((size_t)bb * QQ + r * 16 + i) * SS;  // uniform -> s_load
      float a0 = 0.f;
#pragma unroll
      for (int s = 0; s < 36; ++s) a0 = fmaf(ap[s], ctxreg[s], a0);
      wc[i] = a0;
    }
#pragma unroll
    for (int i = 0; i < 16; ++i)
      A16[(size_t)(r * 16 + i) * 1032 + t] = f2bf(wc[i]);
  }
  __syncthreads();

  // P2: per-row 1/(||wc||+eps); one wave per 4 rows
#pragma unroll
  for (int rr = 0; rr < 4; ++rr) {
    int row = w * 4 + rr;
    float ssum = 0.f;
#pragma unroll
    for (int j = 0; j < 8; ++j) {
      int p = lane + 64 * j;
      unsigned u = *(const unsigned*)(A16 + (size_t)row * 1032 + 2 * p);
      float x = __uint_as_float(u << 16);
      float y = __uint_as_float(u & 0xffff0000u);
      ssum = fmaf(x, x, fmaf(y, y, ssum));
    }
#pragma unroll
    for (int m = 1; m < 64; m <<= 1) ssum += __shfl_xor(ssum, m);
    if (lane == 0) norms[row] = 1.f / (sqrtf(ssum) + 1e-8f);
  }
  __syncthreads();

  // P3: A = (query - wc*rn)^2, bf16 in place
  for (int q2 = 0; q2 < 64; ++q2) {
    float rn = norms[q2];
    float qv = query[((size_t)bb * QQ + q2) * DD + t];
    size_t ai = (size_t)q2 * 1032 + t;
    float av = qv - bf2f(A16[ai]) * rn;
    A16[ai] = f2bf(av * av);
  }
  __syncthreads();

  // P4: GEMM C[64 q][256 k] = A(64x1024) . W^T, K-chunks of 32 staged in LDS
  f32x4 acc[4][4];
#pragma unroll
  for (int mf = 0; mf < 4; ++mf)
#pragma unroll
    for (int nf = 0; nf < 4; ++nf) acc[mf][nf] = (f32x4){0.f, 0.f, 0.f, 0.f};

  const int ml = lane & 15, ko = (lane >> 4) * 8;
  const int n0 = w * 64;                 // compute waves w<4 each own 64 cols
  const int wn = t >> 2, wjs = (t & 3) * 8;  // staging: thread -> (row n, 8 floats)

  float4 wa = *(const float4*)&Wm[(size_t)wn * DD + wjs];
  float4 wb = *(const float4*)&Wm[(size_t)wn * DD + wjs + 4];
  for (int kc = 0; kc < 32; ++kc) {
    u16x8 pk;
    pk[0] = f2bf(wa.x); pk[1] = f2bf(wa.y); pk[2] = f2bf(wa.z); pk[3] = f2bf(wa.w);
    pk[4] = f2bf(wb.x); pk[5] = f2bf(wb.y); pk[6] = f2bf(wb.z); pk[7] = f2bf(wb.w);
    __syncthreads();  // prior chunk's mfma reads done
    *(u16x8*)(Wl + (size_t)wn * 40 + wjs) = pk;
    if (kc < 31) {  // prefetch next chunk (latency overlaps barrier+mfma)
      wa = *(const float4*)&Wm[(size_t)wn * DD + (kc + 1) * 32 + wjs];
      wb = *(const float4*)&Wm[(size_t)wn * DD + (kc + 1) * 32 + wjs + 4];
    }
    __syncthreads();  // Wl ready
    if (w < 4) {
      bf16x8 af[4], bfr[4];
#pragma unroll
      for (int mf = 0; mf < 4; ++mf)
        af[mf] = __builtin_bit_cast(
            bf16x8, *(const u16x8*)(A16 + (size_t)(mf * 16 + ml) * 1032 + kc * 32 + ko));
#pragma unroll
      for (int nf = 0; nf < 4; ++nf)
        bfr[nf] = __builtin_bit_cast(
            bf16x8, *(const u16x8*)(Wl + (size_t)(n0 + nf * 16 + ml) * 40 + ko));
#pragma unroll
      for (int mf = 0; mf < 4; ++mf)
#pragma unroll
        for (int nf = 0; nf < 4; ++nf)
          acc[mf][nf] =
              __builtin_amdgcn_mfma_f32_16x16x32_bf16(af[mf], bfr[nf], acc[mf][nf], 0, 0, 0);
    }
  }
  __syncthreads();

  // P5: spill C to LDS (reuse A region), stride 260 to avoid bank conflicts
  float* Cf = (float*)smem;  // [64][260]
  if (w < 4) {
#pragma unroll
    for (int mf = 0; mf < 4; ++mf)
#pragma unroll
      for (int nf = 0; nf < 4; ++nf)
#pragma unroll
        for (int ii = 0; ii < 4; ++ii) {
          int rrow = mf * 16 + (lane >> 4) * 4 + ii;  // m
          int ccol = n0 + nf * 16 + ml;               // n
          Cf[rrow * 260 + ccol] = acc[mf][nf][ii];
        }
  }
  __syncthreads();

  // P6: +bias, l2norm over 256, store. 16-lane group per output row.
  {
    int g = t >> 4, l16 = t & 15;
    float v[16];
    float ssum = 0.f;
#pragma unroll
    for (int j = 0; j < 16; ++j) {
      int col = l16 + 16 * j;  // strided: bank-conflict-free
      v[j] = Cf[g * 260 + col] + bias[col];
      ssum = fmaf(v[j], v[j], ssum);
    }
#pragma unroll
    for (int m = 1; m < 16; m <<= 1) ssum += __shfl_xor(ssum, m);
    float rn = 1.f / (sqrtf(ssum) + 1e-8f);
    size_t base = ((size_t)bb * QQ + g) * SIM;
#pragma unroll
    for (int j = 0; j < 16; ++j) {
      int col = l16 + 16 * j;
      out[base + col] = v[j] * rn;
    }
  }
}

extern "C" void kernel_launch(void* const* d_in, const int* in_sizes, int n_in,
                              void* d_out, int out_size, void* d_ws, size_t ws_size,
                              hipStream_t stream) {
  const float* query = (const float*)d_in[0];
  const float* context = (const float*)d_in[1];
  const float* matrix = (const float*)d_in[2];
  const float* Wm = (const float*)d_in[3];
  const float* bvec = (const float*)d_in[4];
  const int* smoothp = (const int*)d_in[5];
  float* out = (float*)d_out;
  float* attn = (float*)d_ws;  // needs 512*64*36*4 = 4.72 MB

  // allow >64KB dynamic LDS for k2 (idempotent; not a stream op -> capture-safe)
  hipFuncSetAttribute((const void*)k2_fused,
                      hipFuncAttributeMaxDynamicSharedMemorySize, K2_LDS);

  k1_attn<<<dim3(BB), dim3(256), 0, stream>>>(query, context, matrix, smoothp, attn);
  k2_fused<<<dim3(BB), dim3(1024), K2_LDS, stream>>>(query, context, Wm, bvec, attn, out);
}

// Round 2
// 193.499 us; speedup vs baseline: 2.2948x; 2.2948x over previous
//
#include <hip/hip_runtime.h>
#include <hip/hip_bf16.h>

// Problem dims (fixed by reference): B=512, Q=64, S=36, D=1024, SIM=256
#define BB 512
#define QQ 64
#define SS 36
#define DD 1024
#define SIM 256

typedef unsigned short u16x8 __attribute__((ext_vector_type(8)));
typedef __bf16 bf16x8 __attribute__((ext_vector_type(8)));
typedef float f32x4 __attribute__((ext_vector_type(4)));

__device__ __forceinline__ unsigned short f2bf(float f) {
  unsigned u = __float_as_uint(f);
  u += 0x7FFFu + ((u >> 16) & 1u);   // round-to-nearest-even
  return (unsigned short)(u >> 16);
}
__device__ __forceinline__ float bf2f(unsigned short h) {
  return __uint_as_float(((unsigned)h) << 16);
}

// ---------------------------------------------------------------------------
// K1 (MFMA rewrite): per-batch scores = ctx(36x1024) . qm(64x1024)^T via
// mfma_f32_16x16x32_bf16, M=48 (rows 36-47 zero), N=64, K chunked at 128.
// Then leaky -> l2norm over Q -> softmax over S -> probs (B,Q,S) f32 to ws.
// grid = 512, block = 256 (4 waves; wave w owns n-tile w = 16 q columns).
// LDS: qmL[64][136] bf16 (17408B) | ctxL[48][136] bf16 (13056B) = 30464B.
// sc[48][68] f32 (13056B) aliases qmL region after the GEMM loop.
// Row pitch 136 bf16 (272B): b128 stage-writes and frag-reads both land on
// the optimal 8-slot x 8-lane wave64 pattern (no excess bank conflicts).
// ---------------------------------------------------------------------------
__global__ __launch_bounds__(256) void k1_attn(
    const float* __restrict__ query, const float* __restrict__ context,
    const float* __restrict__ matrix, const int* __restrict__ smoothp,
    float* __restrict__ attn) {
  __shared__ __align__(16) char smem1[30464];
  unsigned short* qmL = (unsigned short*)smem1;            // [64][136]
  unsigned short* ctxL = (unsigned short*)(smem1 + 17408); // [48][136]
  float* sc = (float*)smem1;                               // [48][68] (after GEMM)

  const int t = threadIdx.x;
  const int bb = blockIdx.x;
  const int lane = t & 63, w = t >> 6;
  const int ml = lane & 15, kg = lane >> 4;
  const float smf = (float)smoothp[0];

  f32x4 acc[3];
#pragma unroll
  for (int mt = 0; mt < 3; ++mt) acc[mt] = (f32x4){0.f, 0.f, 0.f, 0.f};

  for (int ch = 0; ch < 8; ++ch) {
    const int d0 = ch * 128;
    // stage qm = query*matrix as bf16: thread -> (row, 8 consecutive d)
#pragma unroll
    for (int i = 0; i < 4; ++i) {
      int idx = t + 256 * i;
      int row = idx >> 4, c8 = idx & 15;
      const float4* gq = (const float4*)&query[((size_t)bb * QQ + row) * DD + d0 + c8 * 8];
      const float4* gm = (const float4*)&matrix[((size_t)bb * QQ + row) * DD + d0 + c8 * 8];
      float4 a0 = gq[0], a1 = gq[1], m0 = gm[0], m1 = gm[1];
      u16x8 pk;
      pk[0] = f2bf(a0.x * m0.x); pk[1] = f2bf(a0.y * m0.y);
      pk[2] = f2bf(a0.z * m0.z); pk[3] = f2bf(a0.w * m0.w);
      pk[4] = f2bf(a1.x * m1.x); pk[5] = f2bf(a1.y * m1.y);
      pk[6] = f2bf(a1.z * m1.z); pk[7] = f2bf(a1.w * m1.w);
      *(u16x8*)&qmL[row * 136 + c8 * 8] = pk;
    }
    // stage ctx bf16 (rows 36-47 zero-padded)
#pragma unroll
    for (int i = 0; i < 3; ++i) {
      int idx = t + 256 * i;
      int row = idx >> 4, c8 = idx & 15;
      u16x8 pk = (u16x8){0, 0, 0, 0, 0, 0, 0, 0};
      if (row < 36) {
        const float4* gc = (const float4*)&context[((size_t)bb * SS + row) * DD + d0 + c8 * 8];
        float4 a0 = gc[0], a1 = gc[1];
        pk[0] = f2bf(a0.x); pk[1] = f2bf(a0.y); pk[2] = f2bf(a0.z); pk[3] = f2bf(a0.w);
        pk[4] = f2bf(a1.x); pk[5] = f2bf(a1.y); pk[6] = f2bf(a1.z); pk[7] = f2bf(a1.w);
      }
      *(u16x8*)&ctxL[row * 136 + c8 * 8] = pk;
    }
    __syncthreads();
    // MFMA: wave w = n-tile (q cols w*16..+16); 3 m-tiles (s rows)
#pragma unroll
    for (int ks = 0; ks < 4; ++ks) {
      const int ko = ks * 32 + kg * 8;
      bf16x8 bfrag = __builtin_bit_cast(bf16x8, *(const u16x8*)&qmL[(w * 16 + ml) * 136 + ko]);
#pragma unroll
      for (int mt = 0; mt < 3; ++mt) {
        bf16x8 afrag =
            __builtin_bit_cast(bf16x8, *(const u16x8*)&ctxL[(mt * 16 + ml) * 136 + ko]);
        acc[mt] = __builtin_amdgcn_mfma_f32_16x16x32_bf16(afrag, bfrag, acc[mt], 0, 0, 0);
      }
    }
    __syncthreads();
  }

  // leaky relu + spill scores to sc[s][q] (aliases qmL; all reads done)
#pragma unroll
  for (int mt = 0; mt < 3; ++mt)
#pragma unroll
    for (int ii = 0; ii < 4; ++ii) {
      float v = acc[mt][ii];
      v = v > 0.f ? v : 0.1f * v;
      sc[(mt * 16 + kg * 4 + ii) * 68 + w * 16 + ml] = v;
    }
  __syncthreads();

  // l2norm over q per row s
  if (t < 36) {
    float ssum = 0.f;
    for (int qi = 0; qi < 64; ++qi) { float v = sc[t * 68 + qi]; ssum = fmaf(v, v, ssum); }
    float rn = 1.f / (sqrtf(ssum) + 1e-8f);
    for (int qi = 0; qi < 64; ++qi) sc[t * 68 + qi] *= rn;
  }
  __syncthreads();

  // softmax over s per column q, write probs to ws (B,Q,S)
  if (t < 64) {
    float mx = -1e30f;
    for (int s2 = 0; s2 < 36; ++s2) mx = fmaxf(mx, sc[s2 * 68 + t]);
    float sum = 0.f;
    float ev[36];
    for (int s2 = 0; s2 < 36; ++s2) {
      float e = __expf((sc[s2 * 68 + t] - mx) * smf);
      ev[s2] = e;
      sum += e;
    }
    float rs = 1.f / sum;
    size_t base = ((size_t)bb * QQ + t) * SS;
    for (int s2 = 0; s2 < 36; ++s2) attn[base + s2] = ev[s2] * rs;
  }
}

// ---------------------------------------------------------------------------
// K2: per-batch wc -> l2norm -> A=(q-wc)^2 (bf16) -> MFMA GEMM with W -> +b,
// l2norm over SIM -> out. grid = 512, block = 1024 (16 waves), dyn LDS.
// LDS layout: A16 [64][1032] bf16 @0 (132096B) | Wl [256][40] bf16 @132096
//             bias[256] f32 @152576 | norms[64] f32 @153600. Total 153856.
// ---------------------------------------------------------------------------
#define K2_LDS 153856

__global__ __launch_bounds__(1024) void k2_fused(
    const float* __restrict__ query, const float* __restrict__ context,
    const float* __restrict__ Wm, const float* __restrict__ bvec,
    const float* __restrict__ attn, float* __restrict__ out) {
  extern __shared__ char smem[];
  unsigned short* A16 = (unsigned short*)smem;             // [64][1032]
  unsigned short* Wl = (unsigned short*)(smem + 132096);   // [256][40]
  float* bias = (float*)(smem + 152576);                   // [256]
  float* norms = (float*)(smem + 153600);                  // [64]

  const int t = threadIdx.x, bb = blockIdx.x;
  const int lane = t & 63, w = t >> 6;

  if (t < 256) bias[t] = bvec[t];

  // context distributed thread<->d: ctxreg[s] = ctx[b][s][t]
  float ctxreg[36];
#pragma unroll
  for (int s = 0; s < 36; ++s)
    ctxreg[s] = context[((size_t)bb * SS + s) * DD + t];

  // P1: wc rows (q in 4 quarters of 16), stash bf16 into A16
  for (int r = 0; r < 4; ++r) {
    float wc[16];
#pragma unroll
    for (int i = 0; i < 16; ++i) {
      const float* ap = attn + ((size_t)bb * QQ + r * 16 + i) * SS;  // uniform -> s_load
      float a0 = 0.f;
#pragma unroll
      for (int s = 0; s < 36; ++s) a0 = fmaf(ap[s], ctxreg[s], a0);
      wc[i] = a0;
    }
#pragma unroll
    for (int i = 0; i < 16; ++i)
      A16[(size_t)(r * 16 + i) * 1032 + t] = f2bf(wc[i]);
  }
  __syncthreads();

  // P2: per-row 1/(||wc||+eps); one wave per 4 rows
#pragma unroll
  for (int rr = 0; rr < 4; ++rr) {
    int row = w * 4 + rr;
    float ssum = 0.f;
#pragma unroll
    for (int j = 0; j < 8; ++j) {
      int p = lane + 64 * j;
      unsigned u = *(const unsigned*)(A16 + (size_t)row * 1032 + 2 * p);
      float x = __uint_as_float(u << 16);
      float y = __uint_as_float(u & 0xffff0000u);
      ssum = fmaf(x, x, fmaf(y, y, ssum));
    }
#pragma unroll
    for (int m = 1; m < 64; m <<= 1) ssum += __shfl_xor(ssum, m);
    if (lane == 0) norms[row] = 1.f / (sqrtf(ssum) + 1e-8f);
  }
  __syncthreads();

  // P3: A = (query - wc*rn)^2, bf16 in place
  for (int q2 = 0; q2 < 64; ++q2) {
    float rn = norms[q2];
    float qv = query[((size_t)bb * QQ + q2) * DD + t];
    size_t ai = (size_t)q2 * 1032 + t;
    float av = qv - bf2f(A16[ai]) * rn;
    A16[ai] = f2bf(av * av);
  }
  __syncthreads();

  // P4: GEMM C[64 q][256 k] = A(64x1024) . W^T, K-chunks of 32 staged in LDS
  f32x4 acc[4][4];
#pragma unroll
  for (int mf = 0; mf < 4; ++mf)
#pragma unroll
    for (int nf = 0; nf < 4; ++nf) acc[mf][nf] = (f32x4){0.f, 0.f, 0.f, 0.f};

  const int ml = lane & 15, ko = (lane >> 4) * 8;
  const int n0 = w * 64;                 // compute waves w<4 each own 64 cols
  const int wn = t >> 2, wjs = (t & 3) * 8;  // staging: thread -> (row n, 8 floats)

  float4 wa = *(const float4*)&Wm[(size_t)wn * DD + wjs];
  float4 wb = *(const float4*)&Wm[(size_t)wn * DD + wjs + 4];
  for (int kc = 0; kc < 32; ++kc) {
    u16x8 pk;
    pk[0] = f2bf(wa.x); pk[1] = f2bf(wa.y); pk[2] = f2bf(wa.z); pk[3] = f2bf(wa.w);
    pk[4] = f2bf(wb.x); pk[5] = f2bf(wb.y); pk[6] = f2bf(wb.z); pk[7] = f2bf(wb.w);
    __syncthreads();  // prior chunk's mfma reads done
    *(u16x8*)(Wl + (size_t)wn * 40 + wjs) = pk;
    if (kc < 31) {  // prefetch next chunk (latency overlaps barrier+mfma)
      wa = *(const float4*)&Wm[(size_t)wn * DD + (kc + 1) * 32 + wjs];
      wb = *(const float4*)&Wm[(size_t)wn * DD + (kc + 1) * 32 + wjs + 4];
    }
    __syncthreads();  // Wl ready
    if (w < 4) {
      bf16x8 af[4], bfr[4];
#pragma unroll
      for (int mf = 0; mf < 4; ++mf)
        af[mf] = __builtin_bit_cast(
            bf16x8, *(const u16x8*)(A16 + (size_t)(mf * 16 + ml) * 1032 + kc * 32 + ko));
#pragma unroll
      for (int nf = 0; nf < 4; ++nf)
        bfr[nf] = __builtin_bit_cast(
            bf16x8, *(const u16x8*)(Wl + (size_t)(n0 + nf * 16 + ml) * 40 + ko));
#pragma unroll
      for (int mf = 0; mf < 4; ++mf)
#pragma unroll
        for (int nf = 0; nf < 4; ++nf)
          acc[mf][nf] =
              __builtin_amdgcn_mfma_f32_16x16x32_bf16(af[mf], bfr[nf], acc[mf][nf], 0, 0, 0);
    }
  }
  __syncthreads();

  // P5: spill C to LDS (reuse A region), stride 260 to avoid bank conflicts
  float* Cf = (float*)smem;  // [64][260]
  if (w < 4) {
#pragma unroll
    for (int mf = 0; mf < 4; ++mf)
#pragma unroll
      for (int nf = 0; nf < 4; ++nf)
#pragma unroll
        for (int ii = 0; ii < 4; ++ii) {
          int rrow = mf * 16 + (lane >> 4) * 4 + ii;  // m
          int ccol = n0 + nf * 16 + ml;               // n
          Cf[rrow * 260 + ccol] = acc[mf][nf][ii];
        }
  }
  __syncthreads();

  // P6: +bias, l2norm over 256, store. 16-lane group per output row.
  {
    int g = t >> 4, l16 = t & 15;
    float v[16];
    float ssum = 0.f;
#pragma unroll
    for (int j = 0; j < 16; ++j) {
      int col = l16 + 16 * j;  // strided: bank-conflict-free
      v[j] = Cf[g * 260 + col] + bias[col];
      ssum = fmaf(v[j], v[j], ssum);
    }
#pragma unroll
    for (int m = 1; m < 16; m <<= 1) ssum += __shfl_xor(ssum, m);
    float rn = 1.f / (sqrtf(ssum) + 1e-8f);
    size_t base = ((size_t)bb * QQ + g) * SIM;
#pragma unroll
    for (int j = 0; j < 16; ++j) {
      int col = l16 + 16 * j;
      out[base + col] = v[j] * rn;
    }
  }
}

extern "C" void kernel_launch(void* const* d_in, const int* in_sizes, int n_in,
                              void* d_out, int out_size, void* d_ws, size_t ws_size,
                              hipStream_t stream) {
  const float* query = (const float*)d_in[0];
  const float* context = (const float*)d_in[1];
  const float* matrix = (const float*)d_in[2];
  const float* Wm = (const float*)d_in[3];
  const float* bvec = (const float*)d_in[4];
  const int* smoothp = (const int*)d_in[5];
  float* out = (float*)d_out;
  float* attn = (float*)d_ws;  // needs 512*64*36*4 = 4.72 MB

  // allow >64KB dynamic LDS for k2 (idempotent; not a stream op -> capture-safe)
  hipFuncSetAttribute((const void*)k2_fused,
                      hipFuncAttributeMaxDynamicSharedMemorySize, K2_LDS);

  k1_attn<<<dim3(BB), dim3(256), 0, stream>>>(query, context, matrix, smoothp, attn);
  k2_fused<<<dim3(BB), dim3(1024), K2_LDS, stream>>>(query, context, Wm, bvec, attn, out);
}